// Round 3
// baseline (179.604 us; speedup 1.0000x reference)
//
#include <hip/hip_runtime.h>
#include <stdint.h>

#define NROWS 4096
#define DIM   512
#define BK    32
#define TILE  64
#define NBLK  64            // NROWS / TILE
#define NPAIR 2080          // NBLK*(NBLK+1)/2
#define KSTEPS (DIM / BK)   // 16

typedef float f32x4 __attribute__((ext_vector_type(4)));
typedef short s16x8 __attribute__((ext_vector_type(8)));

// workspace layout (bytes)
#define OFF_XB   0u
#define OFF_SQ   (NROWS * DIM * 2u)          // 4,194,304
#define OFF_LAB  (OFF_SQ + NROWS * 4u)       // + 16 KB
#define OFF_ACC  (OFF_LAB + NROWS * 4u)      // + 16 KB

__device__ __forceinline__ unsigned short f2bf(float f) {
  unsigned u = __float_as_uint(f);
  return (unsigned short)((u + 0x7FFFu + ((u >> 16) & 1u)) >> 16);
}

typedef __attribute__((address_space(1))) unsigned int glb_uint;
typedef __attribute__((address_space(3))) unsigned int lds_uint;

__device__ __forceinline__ void gl2lds16(const void* g, void* l) {
  __builtin_amdgcn_global_load_lds(
      (glb_uint*)(uintptr_t)g,
      (lds_uint*)(unsigned int)(uintptr_t)l,
      16, 0, 0);
}

// ---------------- prep: fp32 -> bf16, sq rows (fp32 exact), labels -> i32, zero accum
__global__ __launch_bounds__(256) void prep_kernel(
    const float* __restrict__ X, const long long* __restrict__ lab,
    unsigned short* __restrict__ Xb, float* __restrict__ sq,
    int* __restrict__ labi, float* __restrict__ accum)
{
  int t = threadIdx.x;
  int gid = blockIdx.x * 256 + t;
  if (gid < 4) accum[gid] = 0.0f;               // sum1, sum2, cnt(bits), done-counter
  if (gid < NROWS) labi[gid] = (int)lab[gid];

  int wave = t >> 6, lane = t & 63;
  int row = blockIdx.x * 4 + wave;              // 1024 blocks * 4 rows
  const float4* Xr = (const float4*)(X + (size_t)row * DIM);
  float4 a = Xr[lane * 2];
  float4 b = Xr[lane * 2 + 1];

  uint4 pk;
  pk.x = (unsigned)f2bf(a.x) | ((unsigned)f2bf(a.y) << 16);
  pk.y = (unsigned)f2bf(a.z) | ((unsigned)f2bf(a.w) << 16);
  pk.z = (unsigned)f2bf(b.x) | ((unsigned)f2bf(b.y) << 16);
  pk.w = (unsigned)f2bf(b.z) | ((unsigned)f2bf(b.w) << 16);
  *(uint4*)(Xb + (size_t)row * DIM + lane * 8) = pk;

  float s = a.x*a.x + a.y*a.y + a.z*a.z + a.w*a.w
          + b.x*b.x + b.y*b.y + b.z*b.z + b.w*b.w;
  #pragma unroll
  for (int off = 32; off; off >>= 1) s += __shfl_down(s, off, 64);
  if (lane == 0) sq[row] = s;
}

// ---------------- main: symmetric tiled X*X^T, 64x64 tiles for TLP.
// 2080 blocks x 4 waves -> ~8 blocks/CU resident (LDS ~17.5 KB/block):
// per-block load latency is hidden by cross-block wave overlap (m114),
// which the 528-block/128-tile version could not do (2 blocks/CU).
// Coalesced staging (4 lanes share one 64B line) + XOR chunk swizzle that
// permutes lanes only WITHIN their 64B line on the global side:
//   LDS slot (row, ch) holds global chunk ch ^ ((row>>1)&3)
//   fragment read of chunk q of row -> slot row*4 + (q ^ ((row>>1)&3))
// 2-phase double-buffered loop, one barrier per K-step. Fused loss epilogue
// + last-block finalize.
__global__ __launch_bounds__(256) void pair_kernel(
    const unsigned short* __restrict__ Xb, const float* __restrict__ sq,
    const int* __restrict__ labi, const float* __restrict__ marginp,
    float* __restrict__ accum, float* __restrict__ out)
{
  __shared__ unsigned short As[2][TILE * BK];   // 2 x 4 KB
  __shared__ unsigned short Bs[2][TILE * BK];   // 2 x 4 KB
  __shared__ float sRow[TILE], sCol[TILE];
  __shared__ int   lRow[TILE], lCol[TILE];
  __shared__ float rs1[4], rs2[4];
  __shared__ int   rc[4];

  int t = threadIdx.x;

  // linear block -> (bi, bj) with bi <= bj
  int rem = blockIdx.x, bi = 0;
  while (rem >= (NBLK - bi)) { rem -= (NBLK - bi); bi++; }
  int bj = bi + rem;

  int wave = t >> 6, lane = t & 63;
  int quad = lane >> 4, ml = lane & 15;
  int waveRow = (wave >> 1) * 32;               // 0 or 32
  int waveCol = (wave & 1) * 32;                // 0 or 32

  // ---- hoisted epilogue loads: issue NOW, latency hidden under the K-loop
  float margin = *marginp;
  float sqv = 0.f; int lbv = 0;
  if (t < 2 * TILE) {
    int u = t & (TILE - 1);
    int base = (t < TILE ? bi : bj) * TILE + u;
    sqv = sq[base];
    lbv = labi[base];
  }

  // ---- staging: thread t owns LDS slot t (16B) = (row = t>>2, chunk = t&3).
  // Global source chunk XOR-swizzled within the row's 64B group (coalescing intact):
  const int rr = t >> 2;                        // 0..63
  const int cg = (t & 3) ^ ((t >> 3) & 3);      // swizzled chunk, same 64B line
  const size_t gA = (size_t)(bi * TILE + rr) * DIM + cg * 8;
  const size_t gB = (size_t)(bj * TILE + rr) * DIM + cg * 8;

  // read-side swizzle: (row>>1)&3 == (ml>>1)&3 (tile row bases are multiples of 8)
  const int xq = quad ^ ((ml >> 1) & 3);

  f32x4 acc[2][2] = {};

  #define STAGE(buf, kt)                                                      \
    do {                                                                      \
      size_t ko = (size_t)(kt) * BK;                                          \
      gl2lds16(Xb + gA + ko, (void*)(&As[(buf)][t * 8]));                     \
      gl2lds16(Xb + gB + ko, (void*)(&Bs[(buf)][t * 8]));                     \
    } while (0)

  #define COMPUTE(buf)                                                        \
    do {                                                                      \
      const s16x8* Ap = (const s16x8*)As[(buf)];                              \
      const s16x8* Bp = (const s16x8*)Bs[(buf)];                              \
      s16x8 af[2], bfr[2];                                                    \
      _Pragma("unroll")                                                       \
      for (int r = 0; r < 2; ++r)                                             \
        af[r] = Ap[(waveRow + r * 16 + ml) * 4 + xq];                         \
      _Pragma("unroll")                                                       \
      for (int c = 0; c < 2; ++c)                                             \
        bfr[c] = Bp[(waveCol + c * 16 + ml) * 4 + xq];                        \
      _Pragma("unroll")                                                       \
      for (int r = 0; r < 2; ++r)                                             \
        _Pragma("unroll")                                                     \
        for (int c = 0; c < 2; ++c)                                           \
          acc[r][c] = __builtin_amdgcn_mfma_f32_16x16x32_bf16(                \
              af[r], bfr[c], acc[r][c], 0, 0, 0);                             \
    } while (0)

  // ---- 2-phase pipeline: one barrier per K-step
  STAGE(0, 0);
  int cur = 0;
  for (int kt = 0; kt < KSTEPS - 1; ++kt) {
    __syncthreads();              // buf[cur] staged; prev reads of buf[cur^1] done
    STAGE(cur ^ 1, kt + 1);       // next tile's loads fly during the MFMAs below
    COMPUTE(cur);
    cur ^= 1;
  }
  __syncthreads();
  COMPUTE(cur);                   // last tile, no prefetch

  // ---- epilogue: stage sq/label tiles from registers
  if (t < TILE)          { sRow[t] = sqv;        lRow[t] = lbv; }
  else if (t < 2 * TILE) { sCol[t - TILE] = sqv; lCol[t - TILE] = lbv; }
  __syncthreads();

  float s1 = 0.f, s2 = 0.f;
  int cnt = 0;
  #pragma unroll
  for (int c = 0; c < 2; ++c) {
    int col = waveCol + c * 16 + ml;
    float sqc = sCol[col];
    int lc = lCol[col];
    #pragma unroll
    for (int r = 0; r < 2; ++r) {
      int rbase = waveRow + r * 16 + quad * 4;   // C/D layout: row=(lane>>4)*4+reg, col=lane&15
      #pragma unroll
      for (int i = 0; i < 4; ++i) {
        int row = rbase + i;
        float d = sRow[row] + sqc - 2.0f * acc[r][c][i];
        d = fmaxf(d, 0.0f);
        if (lRow[row] == lc) { s1 += d; cnt++; }
        else                 { s2 += fmaxf(margin - d, 0.0f); }
      }
    }
  }

  #pragma unroll
  for (int off = 32; off; off >>= 1) {
    s1  += __shfl_down(s1, off, 64);
    s2  += __shfl_down(s2, off, 64);
    cnt += __shfl_down(cnt, off, 64);
  }
  if (lane == 0) { rs1[wave] = s1; rs2[wave] = s2; rc[wave] = cnt; }
  __syncthreads();
  if (t == 0) {
    float f = (bi == bj) ? 1.f : 2.f;
    float S1 = 0.f, S2 = 0.f;
    int C = 0;
    for (int w = 0; w < 4; ++w) { S1 += rs1[w]; S2 += rs2[w]; C += rc[w]; }
    atomicAdd(&accum[0], S1 * f);
    atomicAdd(&accum[1], S2 * f);
    atomicAdd((unsigned*)accum + 2, (unsigned)C * (unsigned)((bi == bj) ? 1 : 2));
    __threadfence();
    // fused finalize: last block to finish computes the scalar output
    unsigned done = atomicAdd((unsigned*)accum + 3, 1u);
    if (done == NPAIR - 1) {
      __threadfence();
      float S1f = atomicAdd(&accum[0], 0.0f);         // device-scope coherent read
      float S2f = atomicAdd(&accum[1], 0.0f);
      unsigned c1 = atomicAdd((unsigned*)accum + 2, 0u);
      double zn1 = (double)c1;
      double zn2 = (double)NROWS * (double)NROWS - zn1;
      out[0] = (float)(0.5 * ((double)S1f / zn1 + (double)S2f / zn2));
    }
  }
  #undef STAGE
  #undef COMPUTE
}

extern "C" void kernel_launch(void* const* d_in, const int* in_sizes, int n_in,
                              void* d_out, int out_size, void* d_ws, size_t ws_size,
                              hipStream_t stream) {
  const float*     X      = (const float*)d_in[0];
  const long long* lab    = (const long long*)d_in[1];
  const float*     margin = (const float*)d_in[2];
  float*           out    = (float*)d_out;

  char* ws = (char*)d_ws;
  unsigned short* Xb   = (unsigned short*)(ws + OFF_XB);
  float*          sq   = (float*)(ws + OFF_SQ);
  int*            labi = (int*)(ws + OFF_LAB);
  float*          accum= (float*)(ws + OFF_ACC);

  prep_kernel<<<NROWS / 4, 256, 0, stream>>>(X, lab, Xb, sq, labi, accum);
  pair_kernel<<<NPAIR, 256, 0, stream>>>(Xb, sq, labi, margin, accum, out);
}

// Round 4
// 170.984 us; speedup vs baseline: 1.0504x; 1.0504x over previous
//
#include <hip/hip_runtime.h>
#include <stdint.h>

#define NROWS 4096
#define DIM   512
#define TILE  64
#define NBLK  64            // NROWS / TILE
#define NPAIR 2080          // NBLK*(NBLK+1)/2

typedef float f32x4 __attribute__((ext_vector_type(4)));
typedef short s16x8 __attribute__((ext_vector_type(8)));

// workspace layout (bytes)
#define OFF_XB   0u
#define OFF_SQ   (NROWS * DIM * 2u)          // 4,194,304
#define OFF_LAB  (OFF_SQ + NROWS * 4u)       // + 16 KB
#define OFF_ACC  (OFF_LAB + NROWS * 4u)      // + 16 KB

__device__ __forceinline__ unsigned short f2bf(float f) {
  unsigned u = __float_as_uint(f);
  return (unsigned short)((u + 0x7FFFu + ((u >> 16) & 1u)) >> 16);
}

typedef __attribute__((address_space(1))) unsigned int glb_uint;
typedef __attribute__((address_space(3))) unsigned int lds_uint;

__device__ __forceinline__ void gl2lds16(const void* g, void* l) {
  __builtin_amdgcn_global_load_lds(
      (glb_uint*)(uintptr_t)g,
      (lds_uint*)(unsigned int)(uintptr_t)l,
      16, 0, 0);
}

// ---------------- prep: fp32 -> bf16, sq rows (fp32 exact), labels -> i32, zero accum
__global__ __launch_bounds__(256) void prep_kernel(
    const float* __restrict__ X, const long long* __restrict__ lab,
    unsigned short* __restrict__ Xb, float* __restrict__ sq,
    int* __restrict__ labi, float* __restrict__ accum)
{
  int t = threadIdx.x;
  int gid = blockIdx.x * 256 + t;
  if (gid < 4) accum[gid] = 0.0f;               // sum1, sum2, cnt(bits), done-counter
  if (gid < NROWS) labi[gid] = (int)lab[gid];

  int wave = t >> 6, lane = t & 63;
  int row = blockIdx.x * 4 + wave;              // 1024 blocks * 4 rows
  const float4* Xr = (const float4*)(X + (size_t)row * DIM);
  float4 a = Xr[lane * 2];
  float4 b = Xr[lane * 2 + 1];

  uint4 pk;
  pk.x = (unsigned)f2bf(a.x) | ((unsigned)f2bf(a.y) << 16);
  pk.y = (unsigned)f2bf(a.z) | ((unsigned)f2bf(a.w) << 16);
  pk.z = (unsigned)f2bf(b.x) | ((unsigned)f2bf(b.y) << 16);
  pk.w = (unsigned)f2bf(b.z) | ((unsigned)f2bf(b.w) << 16);
  *(uint4*)(Xb + (size_t)row * DIM + lane * 8) = pk;

  float s = a.x*a.x + a.y*a.y + a.z*a.z + a.w*a.w
          + b.x*b.x + b.y*b.y + b.z*b.z + b.w*b.w;
  #pragma unroll
  for (int off = 32; off; off >>= 1) s += __shfl_down(s, off, 64);
  if (lane == 0) sq[row] = s;
}

// ---------------- main: symmetric X*X^T, FULL-K single-stage tiles.
// Measured rounds 1/3: time ~ (#global_load_lds instrs) x ~260cy -- every
// per-K-step barrier+vmcnt(0) exposes the whole load-pipe latency once per
// step per block. Fix: stage the ENTIRE 64x512 A and B panels (128 KB LDS)
// in one burst of 32 coalesced 1KB wave-loads, drain ONCE, then run all 16
// K-substeps barrier-free from LDS. 2-half split overlaps half the staging
// under compute. 1 block/CU (128KB LDS) -- fine, latency exposures per block
// drop 16x.
//
// LDS layout per tile: [half h][row r(64)][32 chunks of 16B], where half h
// covers k in [h*256, h*256+256). Chunk cc of row r holds GLOBAL chunk
// cc ^ (r&15)  (involution; applied on the global source address so the
// global_load_lds destination stays linear). Fragment read of global chunk
// c5 at row: lds chunk = c5 ^ (row&15) = c5 ^ ml -> 16 lanes of a quad hit
// all 8 bank-groups twice (2-way = free, m136). Staging wave-instr covers
// 2 contiguous rows x 32 chunks = 1KB contiguous global (lane-permuted by
// XOR within each row -- same lines, coalescing intact).
__global__ __launch_bounds__(256) void pair_kernel(
    const unsigned short* __restrict__ Xb, const float* __restrict__ sq,
    const int* __restrict__ labi, const float* __restrict__ marginp,
    float* __restrict__ accum, float* __restrict__ out)
{
  __shared__ unsigned short As[2 * 16384];   // 64 KB
  __shared__ unsigned short Bs[2 * 16384];   // 64 KB
  __shared__ float sRow[TILE], sCol[TILE];
  __shared__ int   lRow[TILE], lCol[TILE];
  __shared__ float rs1[4], rs2[4];
  __shared__ int   rc[4];

  int t = threadIdx.x;

  // linear block -> (bi, bj) with bi <= bj
  int rem = blockIdx.x, bi = 0;
  while (rem >= (NBLK - bi)) { rem -= (NBLK - bi); bi++; }
  int bj = bi + rem;

  int wave = t >> 6, lane = t & 63;
  int quad = lane >> 4, ml = lane & 15;
  int waveRow = (wave >> 1) * 32;               // 0 or 32
  int waveCol = (wave & 1) * 32;                // 0 or 32

  float margin = *marginp;

  // epilogue data -> LDS before the first barrier (read after compute)
  if (t < TILE)          { sRow[t] = sq[bi * TILE + t];        lRow[t] = labi[bi * TILE + t]; }
  else if (t < 2 * TILE) { int u = t - TILE;
                           sCol[u] = sq[bj * TILE + u];        lCol[u] = labi[bj * TILE + u]; }

  // staging identities: thread t covers (per iter i, per half h)
  //   row r = i*8 + wave*2 + (lane>>5),  chunk c = lane&31
  //   global chunk = c ^ (r & 15); LDS dest = half*32KB + (i*256 + t)*16B (linear)
  const int w2  = wave * 2 + ((t >> 5) & 1);
  const int c31 = t & 31;
  const size_t rowA = (size_t)(bi * TILE) * DIM;
  const size_t rowB = (size_t)(bj * TILE) * DIM;

  #define STAGE_HALF(h)                                                       \
    _Pragma("unroll")                                                         \
    for (int i = 0; i < 8; ++i) {                                             \
      int r  = i * 8 + w2;                                                    \
      int cs = (c31 ^ (r & 15)) * 8;            /* bf16 offset within half */ \
      size_t go = (size_t)r * DIM + (h) * 256 + cs;                           \
      gl2lds16(Xb + rowA + go, (void*)(&As[(h) * 16384 + i * 2048 + t * 8])); \
      gl2lds16(Xb + rowB + go, (void*)(&Bs[(h) * 16384 + i * 2048 + t * 8])); \
    }

  f32x4 acc[2][2] = {};
  const s16x8* Ap = (const s16x8*)As;
  const s16x8* Bp = (const s16x8*)Bs;

  #define COMPUTE_HALF(h)                                                     \
    _Pragma("unroll")                                                         \
    for (int kk = (h) * 8; kk < (h) * 8 + 8; ++kk) {                          \
      int c5 = ((kk & 7) * 4 + quad) ^ ml;       /* swizzled chunk 0..31 */   \
      s16x8 af[2], bfr[2];                                                    \
      _Pragma("unroll")                                                       \
      for (int r = 0; r < 2; ++r)                                             \
        af[r] = Ap[(h) * 2048 + (waveRow + r * 16 + ml) * 32 + c5];           \
      _Pragma("unroll")                                                       \
      for (int c = 0; c < 2; ++c)                                             \
        bfr[c] = Bp[(h) * 2048 + (waveCol + c * 16 + ml) * 32 + c5];          \
      _Pragma("unroll")                                                       \
      for (int r = 0; r < 2; ++r)                                             \
        _Pragma("unroll")                                                     \
        for (int c = 0; c < 2; ++c)                                           \
          acc[r][c] = __builtin_amdgcn_mfma_f32_16x16x32_bf16(                \
              af[r], bfr[c], acc[r][c], 0, 0, 0);                             \
    }

  STAGE_HALF(0);
  __syncthreads();        // ONE drain for half 0 (+ sRow/sCol writes)
  STAGE_HALF(1);          // half-1 loads fly under half-0 compute
  COMPUTE_HALF(0);        // barrier-free: 8 substeps of ds_read+MFMA
  __syncthreads();        // drain half 1
  COMPUTE_HALF(1);

  // ---- fused loss epilogue
  float s1 = 0.f, s2 = 0.f;
  int cnt = 0;
  #pragma unroll
  for (int c = 0; c < 2; ++c) {
    int col = waveCol + c * 16 + ml;
    float sqc = sCol[col];
    int lc = lCol[col];
    #pragma unroll
    for (int r = 0; r < 2; ++r) {
      int rbase = waveRow + r * 16 + quad * 4;   // C/D layout: row=(lane>>4)*4+reg, col=lane&15
      #pragma unroll
      for (int i = 0; i < 4; ++i) {
        int row = rbase + i;
        float d = sRow[row] + sqc - 2.0f * acc[r][c][i];
        d = fmaxf(d, 0.0f);
        if (lRow[row] == lc) { s1 += d; cnt++; }
        else                 { s2 += fmaxf(margin - d, 0.0f); }
      }
    }
  }

  #pragma unroll
  for (int off = 32; off; off >>= 1) {
    s1  += __shfl_down(s1, off, 64);
    s2  += __shfl_down(s2, off, 64);
    cnt += __shfl_down(cnt, off, 64);
  }
  if (lane == 0) { rs1[wave] = s1; rs2[wave] = s2; rc[wave] = cnt; }
  __syncthreads();
  if (t == 0) {
    float f = (bi == bj) ? 1.f : 2.f;
    float S1 = 0.f, S2 = 0.f;
    int C = 0;
    for (int w = 0; w < 4; ++w) { S1 += rs1[w]; S2 += rs2[w]; C += rc[w]; }
    atomicAdd(&accum[0], S1 * f);
    atomicAdd(&accum[1], S2 * f);
    atomicAdd((unsigned*)accum + 2, (unsigned)C * (unsigned)((bi == bj) ? 1 : 2));
    __threadfence();
    // fused finalize: last block to finish computes the scalar output
    unsigned done = atomicAdd((unsigned*)accum + 3, 1u);
    if (done == NPAIR - 1) {
      __threadfence();
      float S1f = atomicAdd(&accum[0], 0.0f);         // device-scope coherent read
      float S2f = atomicAdd(&accum[1], 0.0f);
      unsigned c1 = atomicAdd((unsigned*)accum + 2, 0u);
      double zn1 = (double)c1;
      double zn2 = (double)NROWS * (double)NROWS - zn1;
      out[0] = (float)(0.5 * ((double)S1f / zn1 + (double)S2f / zn2));
    }
  }
  #undef STAGE_HALF
  #undef COMPUTE_HALF
}

extern "C" void kernel_launch(void* const* d_in, const int* in_sizes, int n_in,
                              void* d_out, int out_size, void* d_ws, size_t ws_size,
                              hipStream_t stream) {
  const float*     X      = (const float*)d_in[0];
  const long long* lab    = (const long long*)d_in[1];
  const float*     margin = (const float*)d_in[2];
  float*           out    = (float*)d_out;

  char* ws = (char*)d_ws;
  unsigned short* Xb   = (unsigned short*)(ws + OFF_XB);
  float*          sq   = (float*)(ws + OFF_SQ);
  int*            labi = (int*)(ws + OFF_LAB);
  float*          accum= (float*)(ws + OFF_ACC);

  prep_kernel<<<NROWS / 4, 256, 0, stream>>>(X, lab, Xb, sq, labi, accum);
  pair_kernel<<<NPAIR, 256, 0, stream>>>(Xb, sq, labi, margin, accum, out);
}

// Round 5
// 111.813 us; speedup vs baseline: 1.6063x; 1.5292x over previous
//
#include <hip/hip_runtime.h>
#include <stdint.h>

#define NROWS 4096
#define DIM   512
#define BK    32
#define TILE  128
#define NBLK  32            // NROWS / TILE
#define NPAIR 528           // NBLK*(NBLK+1)/2
#define KSTEPS (DIM / BK)   // 16
#define PITCH 40            // LDS row pitch in shorts (80 B): pads 64B rows -> <=2-way banks

typedef float f32x4 __attribute__((ext_vector_type(4)));
typedef short s16x8 __attribute__((ext_vector_type(8)));

// workspace layout (bytes)
#define OFF_XB   0u
#define OFF_SQ   (NROWS * DIM * 2u)          // 4,194,304
#define OFF_LAB  (OFF_SQ + NROWS * 4u)       // + 16 KB
#define OFF_ACC  (OFF_LAB + NROWS * 4u)      // + 16 KB

__device__ __forceinline__ unsigned short f2bf(float f) {
  unsigned u = __float_as_uint(f);
  return (unsigned short)((u + 0x7FFFu + ((u >> 16) & 1u)) >> 16);
}

// ---------------- prep: fp32 -> bf16, sq rows (fp32 exact), labels -> i32, zero accum
__global__ __launch_bounds__(256) void prep_kernel(
    const float* __restrict__ X, const long long* __restrict__ lab,
    unsigned short* __restrict__ Xb, float* __restrict__ sq,
    int* __restrict__ labi, float* __restrict__ accum)
{
  int t = threadIdx.x;
  int gid = blockIdx.x * 256 + t;
  if (gid < 4) accum[gid] = 0.0f;               // sum1, sum2, cnt(bits), done-counter
  if (gid < NROWS) labi[gid] = (int)lab[gid];

  int wave = t >> 6, lane = t & 63;
  int row = blockIdx.x * 4 + wave;              // 1024 blocks * 4 rows
  const float4* Xr = (const float4*)(X + (size_t)row * DIM);
  float4 a = Xr[lane * 2];
  float4 b = Xr[lane * 2 + 1];

  uint4 pk;
  pk.x = (unsigned)f2bf(a.x) | ((unsigned)f2bf(a.y) << 16);
  pk.y = (unsigned)f2bf(a.z) | ((unsigned)f2bf(a.w) << 16);
  pk.z = (unsigned)f2bf(b.x) | ((unsigned)f2bf(b.y) << 16);
  pk.w = (unsigned)f2bf(b.z) | ((unsigned)f2bf(b.w) << 16);
  *(uint4*)(Xb + (size_t)row * DIM + lane * 8) = pk;

  float s = a.x*a.x + a.y*a.y + a.z*a.z + a.w*a.w
          + b.x*b.x + b.y*b.y + b.z*b.z + b.w*b.w;
  #pragma unroll
  for (int off = 32; off; off >>= 1) s += __shfl_down(s, off, 64);
  if (lane == 0) sq[row] = s;
}

// ---------------- main: symmetric tiled X*X^T, REGISTER-STAGED LDS.
// Measured rounds 0-4: time ~ #global_load_lds wave-instrs x ~200-260cy/CU,
// regardless of barriers/occupancy/cache residency -- the gl2lds pipe is the
// serializer. This version has ZERO global_load_lds: global_load_dwordx4 ->
// VGPR (pipelined, hidden under compute) -> ds_write_b128 into a +16B-padded
// LDS tile (80B pitch: all LDS ops <=2-way bank aliasing = free).
// 128x128 tile (minimum staged bytes: 135 MB), 1 barrier per K-step,
// double-buffered. Fused loss epilogue + last-block finalize.
__global__ __launch_bounds__(256) void pair_kernel(
    const unsigned short* __restrict__ Xb, const float* __restrict__ sq,
    const int* __restrict__ labi, const float* __restrict__ marginp,
    float* __restrict__ accum, float* __restrict__ out)
{
  __shared__ unsigned short As[2][TILE * PITCH];   // 2 x 10 KB
  __shared__ unsigned short Bs[2][TILE * PITCH];   // 2 x 10 KB
  __shared__ float sRow[TILE], sCol[TILE];
  __shared__ int   lRow[TILE], lCol[TILE];
  __shared__ float rs1[4], rs2[4];
  __shared__ int   rc[4];

  int t = threadIdx.x;

  // linear block -> (bi, bj) with bi <= bj
  int rem = blockIdx.x, bi = 0;
  while (rem >= (NBLK - bi)) { rem -= (NBLK - bi); bi++; }
  int bj = bi + rem;

  int wave = t >> 6, lane = t & 63;
  int quad = lane >> 4, ml = lane & 15;
  int waveRow = (wave >> 1) * 64, waveCol = (wave & 1) * 64;

  // ---- hoisted epilogue loads: in flight under the K-loop
  float margin = *marginp;
  float sqv; int lbv;
  {
    int u = t & 127;
    int base = (t < TILE ? bi : bj) * TILE + u;
    sqv = sq[base];
    lbv = labi[base];
  }

  // ---- staging: thread t owns rows r0=t>>2 and r0+64, 16B chunk (t&3) of each
  // 32B K-chunk... wave covers 16 rows x full 64B line per instr (minimal txns).
  const int r0 = t >> 2;              // 0..63
  const int c0 = (t & 3) * 8;         // element offset in the 32-elem K-chunk
  const size_t gA0 = (size_t)(bi * TILE +      r0) * DIM + c0;
  const size_t gA1 = (size_t)(bi * TILE + 64 + r0) * DIM + c0;
  const size_t gB0 = (size_t)(bj * TILE +      r0) * DIM + c0;
  const size_t gB1 = (size_t)(bj * TILE + 64 + r0) * DIM + c0;
  const int wr0 = r0 * PITCH + c0;          // LDS short offsets (16B aligned)
  const int wr1 = (r0 + 64) * PITCH + c0;

  uint4 rA0, rA1, rB0, rB1;

  #define LOADG(kt)                                                           \
    do {                                                                      \
      size_t ko = (size_t)(kt) * BK;                                          \
      rA0 = *(const uint4*)(Xb + gA0 + ko);                                   \
      rA1 = *(const uint4*)(Xb + gA1 + ko);                                   \
      rB0 = *(const uint4*)(Xb + gB0 + ko);                                   \
      rB1 = *(const uint4*)(Xb + gB1 + ko);                                   \
    } while (0)

  #define WRITELDS(buf)                                                       \
    do {                                                                      \
      *(uint4*)(&As[(buf)][wr0]) = rA0;                                       \
      *(uint4*)(&As[(buf)][wr1]) = rA1;                                       \
      *(uint4*)(&Bs[(buf)][wr0]) = rB0;                                       \
      *(uint4*)(&Bs[(buf)][wr1]) = rB1;                                       \
    } while (0)

  f32x4 acc[4][4] = {};

  #define COMPUTE(buf)                                                        \
    do {                                                                      \
      const unsigned short* Ab = As[(buf)];                                   \
      const unsigned short* Bb = Bs[(buf)];                                   \
      s16x8 af[4], bfr[4];                                                    \
      _Pragma("unroll")                                                       \
      for (int r = 0; r < 4; ++r)                                             \
        af[r] = *(const s16x8*)(Ab + (waveRow + r * 16 + ml) * PITCH + quad * 8); \
      _Pragma("unroll")                                                       \
      for (int c = 0; c < 4; ++c)                                             \
        bfr[c] = *(const s16x8*)(Bb + (waveCol + c * 16 + ml) * PITCH + quad * 8); \
      _Pragma("unroll")                                                       \
      for (int r = 0; r < 4; ++r)                                             \
        _Pragma("unroll")                                                     \
        for (int c = 0; c < 4; ++c)                                           \
          acc[r][c] = __builtin_amdgcn_mfma_f32_16x16x32_bf16(                \
              af[r], bfr[c], acc[r][c], 0, 0, 0);                             \
    } while (0)

  // ---- pipeline: regs hold k+1 while LDS buf[cur] feeds MFMA for k.
  LOADG(0);
  WRITELDS(0);
  __syncthreads();
  int cur = 0;
  #pragma unroll 2
  for (int kt = 0; kt < KSTEPS; ++kt) {
    if (kt + 1 < KSTEPS) LOADG(kt + 1);   // pipelined global loads, no LDS dep
    COMPUTE(cur);                          // ds_read + MFMA hide the load latency
    if (kt + 1 < KSTEPS) {
      WRITELDS(cur ^ 1);                   // vmcnt wait folds in here
      __syncthreads();                     // one barrier per K-step
      cur ^= 1;
    }
  }

  // ---- epilogue: stage sq/label tiles from registers
  if (t < TILE) { sRow[t] = sqv; lRow[t] = lbv; }
  else          { sCol[t - TILE] = sqv; lCol[t - TILE] = lbv; }
  __syncthreads();

  float s1 = 0.f, s2 = 0.f;
  int cnt = 0;
  #pragma unroll
  for (int c = 0; c < 4; ++c) {
    int col = waveCol + c * 16 + ml;
    float sqc = sCol[col];
    int lc = lCol[col];
    #pragma unroll
    for (int r = 0; r < 4; ++r) {
      int rbase = waveRow + r * 16 + quad * 4;   // C/D layout: row=(lane>>4)*4+reg, col=lane&15
      #pragma unroll
      for (int i = 0; i < 4; ++i) {
        int row = rbase + i;
        float d = sRow[row] + sqc - 2.0f * acc[r][c][i];
        d = fmaxf(d, 0.0f);
        if (lRow[row] == lc) { s1 += d; cnt++; }
        else                 { s2 += fmaxf(margin - d, 0.0f); }
      }
    }
  }

  #pragma unroll
  for (int off = 32; off; off >>= 1) {
    s1  += __shfl_down(s1, off, 64);
    s2  += __shfl_down(s2, off, 64);
    cnt += __shfl_down(cnt, off, 64);
  }
  if (lane == 0) { rs1[wave] = s1; rs2[wave] = s2; rc[wave] = cnt; }
  __syncthreads();
  if (t == 0) {
    float f = (bi == bj) ? 1.f : 2.f;
    float S1 = 0.f, S2 = 0.f;
    int C = 0;
    for (int w = 0; w < 4; ++w) { S1 += rs1[w]; S2 += rs2[w]; C += rc[w]; }
    atomicAdd(&accum[0], S1 * f);
    atomicAdd(&accum[1], S2 * f);
    atomicAdd((unsigned*)accum + 2, (unsigned)C * (unsigned)((bi == bj) ? 1 : 2));
    __threadfence();
    // fused finalize: last block to finish computes the scalar output
    unsigned done = atomicAdd((unsigned*)accum + 3, 1u);
    if (done == NPAIR - 1) {
      __threadfence();
      float S1f = atomicAdd(&accum[0], 0.0f);         // device-scope coherent read
      float S2f = atomicAdd(&accum[1], 0.0f);
      unsigned c1 = atomicAdd((unsigned*)accum + 2, 0u);
      double zn1 = (double)c1;
      double zn2 = (double)NROWS * (double)NROWS - zn1;
      out[0] = (float)(0.5 * ((double)S1f / zn1 + (double)S2f / zn2));
    }
  }
  #undef LOADG
  #undef WRITELDS
  #undef COMPUTE
}

extern "C" void kernel_launch(void* const* d_in, const int* in_sizes, int n_in,
                              void* d_out, int out_size, void* d_ws, size_t ws_size,
                              hipStream_t stream) {
  const float*     X      = (const float*)d_in[0];
  const long long* lab    = (const long long*)d_in[1];
  const float*     margin = (const float*)d_in[2];
  float*           out    = (float*)d_out;

  char* ws = (char*)d_ws;
  unsigned short* Xb   = (unsigned short*)(ws + OFF_XB);
  float*          sq   = (float*)(ws + OFF_SQ);
  int*            labi = (int*)(ws + OFF_LAB);
  float*          accum= (float*)(ws + OFF_ACC);

  prep_kernel<<<NROWS / 4, 256, 0, stream>>>(X, lab, Xb, sq, labi, accum);
  pair_kernel<<<NPAIR, 256, 0, stream>>>(Xb, sq, labi, margin, accum, out);
}